// Round 5
// baseline (239.994 us; speedup 1.0000x reference)
//
#include <hip/hip_runtime.h>

// ROI-Align (crop_and_resize pad_border=True, 2x res + 2x2 avg pool) for
// fmap [1,200,304,256] f32, rois [N,4] f32, stride=16, out [N, 256*49] f32
// (NCHW-flattened). Symmetric pad of 1 == clamp(idx-1, 0, dim-1).

#define HH 200
#define WW 304
#define CC 256
#define HP (HH + 2)
#define WP (WW + 2)
#define PS 14          // sample grid (2x resolution)
#define NCELL 49       // 7x7 pooled cells
#define LDS_STRIDE 257 // 49x256 tile padded: bank = (s + c) % 32 on transpose read

__global__ __launch_bounds__(256) void roi_align_kernel(
    const float* __restrict__ fmap,
    const float* __restrict__ rois,
    const int*   __restrict__ stride_p,
    float*       __restrict__ out)
{
    __shared__ float pool[NCELL * LDS_STRIDE];
    __shared__ int   yo0[PS], yo1[PS], xo0[PS], xo1[PS];
    __shared__ float lyv[PS], vyv[PS], lxv[PS], vxv[PS];

    const int t = threadIdx.x;
    const int r = blockIdx.x;

    // ---- per-ROI separable index/weight tables (threads 0..27) ----
    if (t < 2 * PS) {
        const bool isx = (t >= PS);
        const int  i   = isx ? (t - PS) : t;
        const float inv = 1.0f / (float)stride_p[0];
        // padded-image box coords (reference adds +1 after /stride)
        const float a0 = rois[4 * r + (isx ? 0 : 1)] * inv + 1.0f;
        const float a1 = rois[4 * r + (isx ? 2 : 3)] * inv + 1.0f;
        const float sc = (a1 - a0) / (float)PS;
        const float coord = a0 + sc * ((float)i + 0.5f) - 0.5f;
        const int size = isx ? WP : HP;

        const float f0   = floorf(coord);
        const float frac = coord - f0;
        int i0 = (int)f0;
        i0 = min(max(i0, 0), size - 1);
        const int i1 = min(i0 + 1, size - 1);
        const float valid = (coord >= 0.0f && coord <= (float)(size - 1)) ? 1.0f : 0.0f;

        if (isx) {
            const int c0 = min(max(i0 - 1, 0), WW - 1);
            const int c1 = min(max(i1 - 1, 0), WW - 1);
            xo0[i] = c0 * CC;        // element offset of column
            xo1[i] = c1 * CC;
            lxv[i] = frac;
            vxv[i] = valid;
        } else {
            const int r0 = min(max(i0 - 1, 0), HH - 1);
            const int r1 = min(max(i1 - 1, 0), HH - 1);
            yo0[i] = r0 * (WW * CC); // element offset of row
            yo1[i] = r1 * (WW * CC);
            lyv[i] = frac;
            vyv[i] = valid;
        }
    }
    __syncthreads();

    // ---- compute phase: wave = one pooled cell, lane = float4 channel group ----
    const int cg = t & 63;   // channel group: channels [4cg, 4cg+3]
    const int sq = t >> 6;   // which cell residue this wave handles
    const float4* __restrict__ f4 = reinterpret_cast<const float4*>(fmap);

    for (int s = sq; s < NCELL; s += 4) {
        const int py = s / 7;
        const int px = s - py * 7;
        float4 acc = make_float4(0.f, 0.f, 0.f, 0.f);
#pragma unroll
        for (int dy = 0; dy < 2; ++dy) {
            const int   iy = 2 * py + dy;
            const float ly = lyv[iy];
            const float vy = vyv[iy];
            const int   ya = yo0[iy] >> 2;  // float4 units
            const int   yb = yo1[iy] >> 2;
#pragma unroll
            for (int dx = 0; dx < 2; ++dx) {
                const int   ix = 2 * px + dx;
                const float lx = lxv[ix];
                const float vx = vxv[ix];
                const int   xa = xo0[ix] >> 2;
                const int   xb = xo1[ix] >> 2;

                const float m   = 0.25f * vy * vx;       // pool-mean * valid mask
                const float w00 = m * (1.f - ly) * (1.f - lx);
                const float w01 = m * (1.f - ly) * lx;
                const float w10 = m * ly * (1.f - lx);
                const float w11 = m * ly * lx;

                const float4 p00 = f4[ya + xa + cg];
                const float4 p01 = f4[ya + xb + cg];
                const float4 p10 = f4[yb + xa + cg];
                const float4 p11 = f4[yb + xb + cg];

                acc.x += w00 * p00.x + w01 * p01.x + w10 * p10.x + w11 * p11.x;
                acc.y += w00 * p00.y + w01 * p01.y + w10 * p10.y + w11 * p11.y;
                acc.z += w00 * p00.z + w01 * p01.z + w10 * p10.z + w11 * p11.z;
                acc.w += w00 * p00.w + w01 * p01.w + w10 * p10.w + w11 * p11.w;
            }
        }
        float* dst = &pool[s * LDS_STRIDE + 4 * cg];
        dst[0] = acc.x;
        dst[1] = acc.y;
        dst[2] = acc.z;
        dst[3] = acc.w;
    }
    __syncthreads();

    // ---- transpose write: out[r, c, s] = pool[s, c], fully coalesced ----
    const size_t base = (size_t)r * (CC * NCELL);
#pragma unroll 1
    for (int k = 0; k < NCELL; ++k) {
        const int idx = t + (k << 8);     // 0 .. 12543
        const int c  = idx / NCELL;
        const int sp = idx - c * NCELL;
        out[base + idx] = pool[sp * LDS_STRIDE + c];
    }
}

extern "C" void kernel_launch(void* const* d_in, const int* in_sizes, int n_in,
                              void* d_out, int out_size, void* d_ws, size_t ws_size,
                              hipStream_t stream) {
    const float* fmap   = (const float*)d_in[0];
    const float* rois   = (const float*)d_in[1];
    const int*   strd   = (const int*)d_in[2];
    float*       out    = (float*)d_out;
    const int n = in_sizes[1] / 4;
    roi_align_kernel<<<n, 256, 0, stream>>>(fmap, rois, strd, out);
}

// Round 6
// 204.651 us; speedup vs baseline: 1.1727x; 1.1727x over previous
//
#include <hip/hip_runtime.h>

// ROI-Align (crop_and_resize pad_border=True, 2x res + 2x2 avg pool) for
// fmap [1,200,304,256] f32, rois [N,4] f32, stride=16, out [N, 256*49] f32
// (NCHW-flattened). Symmetric pad of 1 == clamp(idx-1, 0, dim-1).
//
// R5 profile: dur 133us, FETCH 396MB (6.4x fmap), VALUBusy 21%, Occ 27%
//  -> L2-miss latency bound. This round: Morton-sort ROIs (1-block counting
//     sort into d_ws) + bijective XCD-chunk swizzle (contiguous sorted range
//     per XCD L2) + 2-cell ILP (32 outstanding loads/wave).

#define HH 200
#define WW 304
#define CC 256
#define HP (HH + 2)
#define WP (WW + 2)
#define PS 14          // sample grid (2x resolution)
#define NCELL 49       // 7x7 pooled cells
#define LDS_STRIDE 257 // 49x256 tile padded: bank = (s + c) % 32 on transpose read
#define NBUCKET 256    // 16x16 morton tiles

// ---------- one-block counting sort: perm[sorted_pos] = roi_idx ----------
__global__ __launch_bounds__(256) void roi_sort_kernel(
    const float* __restrict__ rois,
    const int*   __restrict__ stride_p,
    int n, int* __restrict__ perm)
{
    __shared__ int hist[NBUCKET];
    __shared__ int scan[NBUCKET];
    __shared__ int offs[NBUCKET];
    const int t = threadIdx.x;
    hist[t] = 0;
    __syncthreads();

    const float inv = 1.0f / (float)stride_p[0];
    auto key_of = [&](int i) -> int {
        const float cx = 0.5f * (rois[4 * i + 0] + rois[4 * i + 2]) * inv;
        const float cy = 0.5f * (rois[4 * i + 1] + rois[4 * i + 3]) * inv;
        int tx = (int)(cx * (16.0f / (float)WW));
        int ty = (int)(cy * (16.0f / (float)HH));
        tx = min(max(tx, 0), 15);
        ty = min(max(ty, 0), 15);
        int k = 0;
#pragma unroll
        for (int b = 0; b < 4; ++b)
            k |= (((tx >> b) & 1) << (2 * b)) | (((ty >> b) & 1) << (2 * b + 1));
        return k;
    };

    for (int i = t; i < n; i += 256) atomicAdd(&hist[key_of(i)], 1);
    __syncthreads();

    // Hillis-Steele inclusive scan over 256 buckets
    scan[t] = hist[t];
    __syncthreads();
    for (int d = 1; d < NBUCKET; d <<= 1) {
        const int x = (t >= d) ? scan[t - d] : 0;
        __syncthreads();
        scan[t] += x;
        __syncthreads();
    }
    offs[t] = scan[t] - hist[t];   // exclusive
    __syncthreads();

    for (int i = t; i < n; i += 256) {
        const int pos = atomicAdd(&offs[key_of(i)], 1);
        perm[pos] = i;
    }
}

// ---------- main kernel ----------
__global__ __launch_bounds__(256) void roi_align_kernel(
    const float* __restrict__ fmap,
    const float* __restrict__ rois,
    const int*   __restrict__ stride_p,
    const int*   __restrict__ perm,
    int nwg,
    float*       __restrict__ out)
{
    __shared__ float pool[NCELL * LDS_STRIDE];
    __shared__ int   yo0[PS], yo1[PS], xo0[PS], xo1[PS];
    __shared__ float lyv[PS], vyv[PS], lxv[PS], vxv[PS];

    const int t = threadIdx.x;

    // bijective XCD-chunk swizzle: XCD k gets a contiguous sorted range
    const int bid = blockIdx.x;
    const int q = nwg >> 3, rem = nwg & 7;
    const int xcd = bid & 7, idx8 = bid >> 3;
    const int swz = (xcd < rem ? xcd * (q + 1) : rem * (q + 1) + (xcd - rem) * q) + idx8;
    const int r = perm[swz];

    // ---- per-ROI separable index/weight tables (threads 0..27) ----
    if (t < 2 * PS) {
        const bool isx = (t >= PS);
        const int  i   = isx ? (t - PS) : t;
        const float inv = 1.0f / (float)stride_p[0];
        const float a0 = rois[4 * r + (isx ? 0 : 1)] * inv + 1.0f;
        const float a1 = rois[4 * r + (isx ? 2 : 3)] * inv + 1.0f;
        const float sc = (a1 - a0) / (float)PS;
        const float coord = a0 + sc * ((float)i + 0.5f) - 0.5f;
        const int size = isx ? WP : HP;

        const float f0   = floorf(coord);
        const float frac = coord - f0;
        int i0 = (int)f0;
        i0 = min(max(i0, 0), size - 1);
        const int i1 = min(i0 + 1, size - 1);
        const float valid = (coord >= 0.0f && coord <= (float)(size - 1)) ? 1.0f : 0.0f;

        if (isx) {
            const int c0 = min(max(i0 - 1, 0), WW - 1);
            const int c1 = min(max(i1 - 1, 0), WW - 1);
            xo0[i] = c0 * CC;
            xo1[i] = c1 * CC;
            lxv[i] = frac;
            vxv[i] = valid;
        } else {
            const int r0 = min(max(i0 - 1, 0), HH - 1);
            const int r1 = min(max(i1 - 1, 0), HH - 1);
            yo0[i] = r0 * (WW * CC);
            yo1[i] = r1 * (WW * CC);
            lyv[i] = frac;
            vyv[i] = valid;
        }
    }
    __syncthreads();

    // ---- compute: wave pair-processes 2 cells (32 loads in flight) ----
    const int cg = t & 63;   // float4 channel group
    const int sq = t >> 6;
    const float4* __restrict__ f4 = reinterpret_cast<const float4*>(fmap);

    for (int ss = sq; ss < NCELL; ss += 8) {
        const int  s0   = ss;
        const bool has1 = (ss + 4) < NCELL;
        const int  s1   = has1 ? ss + 4 : ss;   // dup-safe
        const int py0 = s0 / 7, px0 = s0 - py0 * 7;
        const int py1 = s1 / 7, px1 = s1 - py1 * 7;
        float4 acc0 = make_float4(0.f, 0.f, 0.f, 0.f);
        float4 acc1 = make_float4(0.f, 0.f, 0.f, 0.f);
#pragma unroll
        for (int dy = 0; dy < 2; ++dy) {
            const int iy0 = 2 * py0 + dy,      iy1 = 2 * py1 + dy;
            const float ly0 = lyv[iy0],        ly1 = lyv[iy1];
            const float vy0 = vyv[iy0],        vy1 = vyv[iy1];
            const int ya0 = yo0[iy0] >> 2,     ya1 = yo0[iy1] >> 2;
            const int yb0 = yo1[iy0] >> 2,     yb1 = yo1[iy1] >> 2;
#pragma unroll
            for (int dx = 0; dx < 2; ++dx) {
                const int ix0 = 2 * px0 + dx,  ix1 = 2 * px1 + dx;
                const float lx0 = lxv[ix0],    lx1 = lxv[ix1];
                const float vx0 = vxv[ix0],    vx1 = vxv[ix1];
                const int xa0 = xo0[ix0] >> 2, xa1 = xo0[ix1] >> 2;
                const int xb0 = xo1[ix0] >> 2, xb1 = xo1[ix1] >> 2;

                const float4 a00 = f4[ya0 + xa0 + cg];
                const float4 a01 = f4[ya0 + xb0 + cg];
                const float4 a10 = f4[yb0 + xa0 + cg];
                const float4 a11 = f4[yb0 + xb0 + cg];
                const float4 b00 = f4[ya1 + xa1 + cg];
                const float4 b01 = f4[ya1 + xb1 + cg];
                const float4 b10 = f4[yb1 + xa1 + cg];
                const float4 b11 = f4[yb1 + xb1 + cg];

                const float m0   = 0.25f * vy0 * vx0;
                const float w00a = m0 * (1.f - ly0) * (1.f - lx0);
                const float w01a = m0 * (1.f - ly0) * lx0;
                const float w10a = m0 * ly0 * (1.f - lx0);
                const float w11a = m0 * ly0 * lx0;
                const float m1   = 0.25f * vy1 * vx1;
                const float w00b = m1 * (1.f - ly1) * (1.f - lx1);
                const float w01b = m1 * (1.f - ly1) * lx1;
                const float w10b = m1 * ly1 * (1.f - lx1);
                const float w11b = m1 * ly1 * lx1;

                acc0.x += w00a * a00.x + w01a * a01.x + w10a * a10.x + w11a * a11.x;
                acc0.y += w00a * a00.y + w01a * a01.y + w10a * a10.y + w11a * a11.y;
                acc0.z += w00a * a00.z + w01a * a01.z + w10a * a10.z + w11a * a11.z;
                acc0.w += w00a * a00.w + w01a * a01.w + w10a * a10.w + w11a * a11.w;
                acc1.x += w00b * b00.x + w01b * b01.x + w10b * b10.x + w11b * b11.x;
                acc1.y += w00b * b00.y + w01b * b01.y + w10b * b10.y + w11b * b11.y;
                acc1.z += w00b * b00.z + w01b * b01.z + w10b * b10.z + w11b * b11.z;
                acc1.w += w00b * b00.w + w01b * b01.w + w10b * b10.w + w11b * b11.w;
            }
        }
        {
            float* d0 = &pool[s0 * LDS_STRIDE + 4 * cg];
            d0[0] = acc0.x; d0[1] = acc0.y; d0[2] = acc0.z; d0[3] = acc0.w;
        }
        if (has1) {
            float* d1 = &pool[s1 * LDS_STRIDE + 4 * cg];
            d1[0] = acc1.x; d1[1] = acc1.y; d1[2] = acc1.z; d1[3] = acc1.w;
        }
    }
    __syncthreads();

    // ---- transpose write: out[r, c, s] = pool[s, c], fully coalesced ----
    const size_t base = (size_t)r * (CC * NCELL);
#pragma unroll 1
    for (int k = 0; k < NCELL; ++k) {
        const int idx = t + (k << 8);     // 0 .. 12543
        const int c  = idx / NCELL;
        const int sp = idx - c * NCELL;
        out[base + idx] = pool[sp * LDS_STRIDE + c];
    }
}

extern "C" void kernel_launch(void* const* d_in, const int* in_sizes, int n_in,
                              void* d_out, int out_size, void* d_ws, size_t ws_size,
                              hipStream_t stream) {
    const float* fmap = (const float*)d_in[0];
    const float* rois = (const float*)d_in[1];
    const int*   strd = (const int*)d_in[2];
    float*       out  = (float*)d_out;
    int*         perm = (int*)d_ws;
    const int n = in_sizes[1] / 4;

    roi_sort_kernel<<<1, 256, 0, stream>>>(rois, strd, n, perm);
    roi_align_kernel<<<n, 256, 0, stream>>>(fmap, rois, strd, perm, n, out);
}